// Round 1
// 475.108 us; speedup vs baseline: 1.1001x; 1.1001x over previous
//
#include <hip/hip_runtime.h>
#include <hip/hip_bf16.h>

// Problem constants
constexpr int kD  = 768;
constexpr int kH  = 12;
constexpr int kDH = 64;
constexpr int kS  = 1500;
constexpr int kSP = 1504;        // S padded to multiple of 32 (47*32)
constexpr int kB  = 8;
constexpr int kM  = kB * kS;     // 12000 rows for the projections
constexpr float kScale = 0.125f;
constexpr int kPSTR = 72;        // P row stride (elems): 144B -> b64/b128 aligned

typedef __bf16 bf16;
typedef __bf16 bf16x4 __attribute__((ext_vector_type(4)));
typedef __bf16 bf16x8 __attribute__((ext_vector_type(8)));
typedef float  floatx4 __attribute__((ext_vector_type(4)));

// ---------------------------------------------------------------------------
// Dtype probe (round-1 NaN proved inputs are f32; cheap guard retained).
// ---------------------------------------------------------------------------
__global__ __launch_bounds__(256) void detect_kernel(const void* __restrict__ xraw,
                                                     int* __restrict__ flag) {
    __shared__ int bad;
    if (threadIdx.x == 0) bad = 0;
    __syncthreads();
    const bf16* xb = (const bf16*)xraw;
    int c = 0;
    for (int k = 0; k < 16; k++) {
        int idx = 2 * (threadIdx.x + 256 * k);
        float v = fabsf((float)xb[idx]);
        if (!(v == 0.0f || (v > 1e-20f && v < 1e6f))) c++;
    }
    atomicAdd(&bad, c);
    __syncthreads();
    if (threadIdx.x == 0) *flag = (bad > 8) ? 1 : 0;
}

__global__ __launch_bounds__(256) void cvt_bf16_kernel(const void* __restrict__ src,
                                                       bf16* __restrict__ dst, int n,
                                                       const int* __restrict__ flag) {
    int i = blockIdx.x * 256 + threadIdx.x;
    if (i < n) {
        if (*flag)
            dst[i] = (bf16)((const float*)src)[i];
        else
            dst[i] = ((const bf16*)src)[i];
    }
}

__global__ __launch_bounds__(256) void cvt_f32_kernel(const void* __restrict__ src,
                                                      float* __restrict__ dst, int n,
                                                      const int* __restrict__ flag) {
    int i = blockIdx.x * 256 + threadIdx.x;
    if (i < n) {
        if (*flag)
            dst[i] = ((const float*)src)[i];
        else
            dst[i] = (float)((const bf16*)src)[i];
    }
}

// ---------------------------------------------------------------------------
// Zero the S-padding rows of q/k and padding cols of v^T.
// ---------------------------------------------------------------------------
__global__ __launch_bounds__(256) void zeropad_kernel(bf16* __restrict__ q_ws,
                                                      bf16* __restrict__ k_ws,
                                                      bf16* __restrict__ vt_ws) {
    int t = blockIdx.x * 256 + threadIdx.x;          // 96 bh * 4 s * 64 dh = 24576
    if (t < kB * kH * (kSP - kS) * kDH) {
        int bh  = t >> 8;
        int rem = t & 255;
        int s   = kS + (rem >> 6);
        int dh  = rem & 63;
        size_t qi = ((size_t)bh * kSP + s) * kDH + dh;
        q_ws[qi] = (bf16)0.f;
        k_ws[qi] = (bf16)0.f;
        size_t vi = ((size_t)bh * kDH + dh) * kSP + s;
        vt_ws[vi] = (bf16)0.f;
    }
}

// ---------------------------------------------------------------------------
// m97-structure GEMM core: 128x128 tile, BK=32, 4 waves, 4x4 acc per wave,
// global_load_lds width-16 staging into linear LDS (lane-order contiguous).
// Per wave per K-step: 4 global_load_lds_dwordx4 + 8 ds_read_b128 + 16 MFMA.
// Out-of-range M rows read garbage (still inside d_ws) and are masked on
// store; MFMA rows are independent so garbage cannot contaminate valid rows.
// ---------------------------------------------------------------------------
__device__ __forceinline__ void async_copy16(const bf16* g, bf16* l) {
    __builtin_amdgcn_global_load_lds(
        (const __attribute__((address_space(1))) void*)g,
        (__attribute__((address_space(3))) void*)l,
        16, 0, 0);
}

__device__ __forceinline__ void gemm128_core(const bf16* __restrict__ X,
                                             const bf16* __restrict__ W,
                                             int m0, int n0,
                                             bf16* Asm, bf16* Bsm,
                                             floatx4 acc[4][4]) {
    const int tid  = threadIdx.x;
    const int lane = tid & 63;
    const int w    = tid >> 6;
    // staging map: wave w, lane l, issue i -> row = i*64 + w*16 + l/4,
    // col = (l%4)*8.  LDS elem offset = i*2048 + w*512 + l*8  (linear in lane).
    const int srow = (w << 4) + (lane >> 2);
    const int scol = (lane & 3) << 3;
    const int lrow = lane & 15;
    const int lq   = lane >> 4;
    const int wm   = (w >> 1) << 6;
    const int wn   = (w & 1) << 6;

    const bf16* gA = X + (size_t)(m0 + srow) * kD + scol;
    const bf16* gB = W + (size_t)(n0 + srow) * kD + scol;
    bf16* lA = Asm + (w << 9);     // wave-uniform base; HW adds lane*16B
    bf16* lB = Bsm + (w << 9);

    for (int k0 = 0; k0 < kD; k0 += 32) {
        async_copy16(gA + k0, lA);
        async_copy16(gA + (size_t)64 * kD + k0, lA + 2048);
        async_copy16(gB + k0, lB);
        async_copy16(gB + (size_t)64 * kD + k0, lB + 2048);
        __syncthreads();   // compiler emits vmcnt(0) drain before barrier

        bf16x8 af[4], bfr[4];
#pragma unroll
        for (int i = 0; i < 4; i++)
            af[i] = *(const bf16x8*)(Asm + ((wm + i * 16 + lrow) << 5) + (lq << 3));
#pragma unroll
        for (int j = 0; j < 4; j++)
            bfr[j] = *(const bf16x8*)(Bsm + ((wn + j * 16 + lrow) << 5) + (lq << 3));
#pragma unroll
        for (int i = 0; i < 4; i++)
#pragma unroll
            for (int j = 0; j < 4; j++)
                acc[i][j] = __builtin_amdgcn_mfma_f32_16x16x32_bf16(
                    af[i], bfr[j], acc[i][j], 0, 0, 0);
        __syncthreads();
    }
}

// Fused QKV projection: grid (94, 18); blockIdx.y/6 selects the matrix
// (0=Q scale+bias, 1=K plain, 2=V bias+transpose), blockIdx.y%6 the n-block.
// 1692 blocks (~6.6/CU) vs 564 for a single matrix -> hides latency.
__global__ __launch_bounds__(256) void qkv_kernel(const bf16* __restrict__ X,
                                                  const bf16* __restrict__ Wq,
                                                  const bf16* __restrict__ Wk,
                                                  const bf16* __restrict__ Wv,
                                                  const float* __restrict__ bq,
                                                  const float* __restrict__ bv,
                                                  bf16* __restrict__ q_ws,
                                                  bf16* __restrict__ k_ws,
                                                  bf16* __restrict__ vt_ws) {
    __shared__ bf16 Asm[128 * 32];
    __shared__ bf16 Bsm[128 * 32];

    const int m0  = blockIdx.x << 7;
    const int mat = blockIdx.y / 6;
    const int n0  = (blockIdx.y % 6) << 7;
    const bf16* W = (mat == 0) ? Wq : (mat == 1) ? Wk : Wv;

    floatx4 acc[4][4] = {};
    gemm128_core(X, W, m0, n0, Asm, Bsm, acc);

    const int tid  = threadIdx.x;
    const int lane = tid & 63;
    const int w    = tid >> 6;
    const int lrow = lane & 15;
    const int lq   = lane >> 4;
    const int wm   = (w >> 1) << 6;
    const int wn   = (w & 1) << 6;

#pragma unroll
    for (int i = 0; i < 4; i++) {
#pragma unroll
        for (int j = 0; j < 4; j++) {
            const int n  = n0 + wn + j * 16 + lrow;
            const int hh = n >> 6, dh = n & 63;
            const float bval = (mat == 0) ? bq[n] : (mat == 2) ? bv[n] : 0.f;
#pragma unroll
            for (int r = 0; r < 4; r++) {
                const int m = m0 + wm + i * 16 + lq * 4 + r;
                if (m >= kM) continue;
                float v = acc[i][j][r];
                if (mat == 0)      v = (v + bval) * kScale;
                else if (mat == 2) v = v + bval;
                const int bb = m / kS, s = m - bb * kS;
                if (mat == 2)
                    vt_ws[(((size_t)(bb * kH + hh)) * kDH + dh) * kSP + s] = (bf16)v;
                else if (mat == 1)
                    k_ws[(((size_t)(bb * kH + hh)) * kSP + s) * kDH + dh] = (bf16)v;
                else
                    q_ws[(((size_t)(bb * kH + hh)) * kSP + s) * kDH + dh] = (bf16)v;
            }
        }
    }
}

// Output projection: grid (94, 6), f32 output with bias.
__global__ __launch_bounds__(256) void out_kernel(const bf16* __restrict__ X,
                                                  const bf16* __restrict__ Wo,
                                                  const float* __restrict__ bo,
                                                  float* __restrict__ outf) {
    __shared__ bf16 Asm[128 * 32];
    __shared__ bf16 Bsm[128 * 32];

    const int m0 = blockIdx.x << 7;
    const int n0 = blockIdx.y << 7;

    floatx4 acc[4][4] = {};
    gemm128_core(X, Wo, m0, n0, Asm, Bsm, acc);

    const int tid  = threadIdx.x;
    const int lane = tid & 63;
    const int w    = tid >> 6;
    const int lrow = lane & 15;
    const int lq   = lane >> 4;
    const int wm   = (w >> 1) << 6;
    const int wn   = (w & 1) << 6;

#pragma unroll
    for (int i = 0; i < 4; i++) {
#pragma unroll
        for (int j = 0; j < 4; j++) {
            const int n = n0 + wn + j * 16 + lrow;
            const float bval = bo[n];
#pragma unroll
            for (int r = 0; r < 4; r++) {
                const int m = m0 + wm + i * 16 + lq * 4 + r;
                if (m >= kM) continue;
                outf[(size_t)m * kD + n] = acc[i][j][r] + bval;
            }
        }
    }
}

// ---------------------------------------------------------------------------
// Flash attention v4 (UNCHANGED this round): v3's dataflow (transposed QK,
// no-max softmax, b64 P write + b128 P read, K=32 PV) with 2 Q-tiles per
// wave. Block covers 128 Q rows; grid idx = qb*96 + bh so idx%8 == bh%8
// keeps each bh's K/V resident in one XCD's L2.
// ---------------------------------------------------------------------------
template <int NT, bool MASK>
__device__ __forceinline__ void attn_chunk(int s0,
                                           const bf16* __restrict__ kbase,
                                           const bf16* __restrict__ vbase,
                                           bf16* __restrict__ P,
                                           const bf16x8 qf[2][2],
                                           float lsum[2], floatx4 Oacc[2][4],
                                           int col, int quad) {
#pragma unroll
    for (int t = 0; t < NT; t++) {
        const bf16* kr = kbase + (size_t)(s0 + 16 * t + col) * kDH + quad * 8;
        const bf16x8 kf0 = *(const bf16x8*)(kr);
        const bf16x8 kf1 = *(const bf16x8*)(kr + 32);
#pragma unroll
        for (int qt = 0; qt < 2; qt++) {
            floatx4 sc = {0.f, 0.f, 0.f, 0.f};
            sc = __builtin_amdgcn_mfma_f32_16x16x32_bf16(kf0, qf[qt][0], sc, 0, 0, 0);
            sc = __builtin_amdgcn_mfma_f32_16x16x32_bf16(kf1, qf[qt][1], sc, 0, 0, 0);
            bf16x4 pv;
#pragma unroll
            for (int r = 0; r < 4; r++) {
                float p;
                if (MASK && (s0 + 16 * t + quad * 4 + r >= kS))
                    p = 0.f;
                else
                    p = __expf(sc[r]);
                lsum[qt] += p;
                pv[r] = (bf16)p;
            }
            *(bf16x4*)(P + (qt * 16 + col) * kPSTR + 16 * t + quad * 4) = pv;
        }
    }
    constexpr int KC = NT / 2;
    bf16x8 pa[2][KC];
#pragma unroll
    for (int qt = 0; qt < 2; qt++)
#pragma unroll
        for (int kc = 0; kc < KC; kc++)
            pa[qt][kc] = *(const bf16x8*)(P + (qt * 16 + col) * kPSTR + kc * 32 + quad * 8);
#pragma unroll
    for (int n = 0; n < 4; n++) {
        const bf16* vr = vbase + (size_t)(n * 16 + col) * kSP + s0 + quad * 8;
#pragma unroll
        for (int kc = 0; kc < KC; kc++) {
            const bf16x8 vf = *(const bf16x8*)(vr + kc * 32);
#pragma unroll
            for (int qt = 0; qt < 2; qt++)
                Oacc[qt][n] = __builtin_amdgcn_mfma_f32_16x16x32_bf16(
                    pa[qt][kc], vf, Oacc[qt][n], 0, 0, 0);
        }
    }
}

__global__ __launch_bounds__(256) void fattn_kernel(const bf16* __restrict__ q_ws,
                                                    const bf16* __restrict__ k_ws,
                                                    const bf16* __restrict__ vt_ws,
                                                    bf16* __restrict__ ctx) {
    __shared__ bf16 Pbuf[4][32 * kPSTR];   // 18432 B, per-wave slices

    const int idx = blockIdx.x;         // 0..1151; bh fastest -> idx%8 = bh%8 (XCD)
    const int bh  = idx % 96;
    const int qb  = idx / 96;           // 0..11, 128 Q rows per block
    const int b   = bh / kH;
    const int h   = bh - b * kH;
    const int tid  = threadIdx.x;
    const int w    = tid >> 6;
    const int lane = tid & 63;
    const int col  = lane & 15;         // q index within a 16-row tile
    const int quad = lane >> 4;
    const int q0   = qb * 128 + w * 32; // this wave's 32 Q rows (2 tiles)
    if (q0 >= kS) return;               // no barriers below: divergent exit OK

    const bf16* qbase = q_ws  + (size_t)bh * kSP * kDH;
    const bf16* kbase = k_ws  + (size_t)bh * kSP * kDH;
    const bf16* vbase = vt_ws + (size_t)bh * kDH * kSP;

    bf16x8 qf[2][2];
#pragma unroll
    for (int qt = 0; qt < 2; qt++) {
        const bf16* qr = qbase + (size_t)(q0 + qt * 16 + col) * kDH + quad * 8;
        qf[qt][0] = *(const bf16x8*)(qr);
        qf[qt][1] = *(const bf16x8*)(qr + 32);
    }

    float lsum[2] = {0.f, 0.f};
    floatx4 Oacc[2][4];
#pragma unroll
    for (int qt = 0; qt < 2; qt++)
#pragma unroll
        for (int n = 0; n < 4; n++) Oacc[qt][n] = (floatx4){0.f, 0.f, 0.f, 0.f};

    bf16* P = &Pbuf[w][0];

    // 23 full 64-key chunks (keys 0..1471), then 32-key masked tail
    for (int s0 = 0; s0 < 1472; s0 += 64)
        attn_chunk<4, false>(s0, kbase, vbase, P, qf, lsum, Oacc, col, quad);
    attn_chunk<2, true>(1472, kbase, vbase, P, qf, lsum, Oacc, col, quad);

#pragma unroll
    for (int qt = 0; qt < 2; qt++) {
        float l = lsum[qt];
        l += __shfl_xor(l, 16);
        l += __shfl_xor(l, 32);
        const float rinv_col = 1.0f / l;             // for q = col of this tile
        float ri[4];
#pragma unroll
        for (int r = 0; r < 4; r++)
            ri[r] = __shfl(rinv_col, quad * 4 + r, 16);
#pragma unroll
        for (int n = 0; n < 4; n++)
#pragma unroll
            for (int r = 0; r < 4; r++) {
                const int q = q0 + qt * 16 + quad * 4 + r;
                if (q < kS)
                    ctx[((size_t)(b * kS + q)) * kD + h * kDH + n * 16 + col] =
                        (bf16)(Oacc[qt][n][r] * ri[r]);
            }
    }
}

// ---------------------------------------------------------------------------
extern "C" void kernel_launch(void* const* d_in, const int* in_sizes, int n_in,
                              void* d_out, int out_size, void* d_ws, size_t ws_size,
                              hipStream_t stream) {
    float* out_f = (float*)d_out;   // reference output dtype is float32

    constexpr size_t nX = (size_t)kM * kD;
    constexpr size_t nW = (size_t)kD * kD;
    constexpr size_t per_qkv = (size_t)kB * kH * kSP * kDH;

    bf16* xb    = (bf16*)d_ws;
    bf16* Wqb   = xb + nX;
    bf16* Wkb   = Wqb + nW;
    bf16* Wvb   = Wkb + nW;
    bf16* Wob   = Wvb + nW;
    bf16* q_ws  = Wob + nW;
    bf16* k_ws  = q_ws + per_qkv;
    bf16* vt_ws = k_ws + per_qkv;
    float* bqf  = (float*)(vt_ws + per_qkv);
    float* bvf  = bqf + kD;
    float* bof  = bvf + kD;
    int*  flag  = (int*)(bof + kD);
    bf16* ctx   = xb;   // alias: xb last read by qkv_kernel, ctx written after

    // 1) dtype probe + input normalization to bf16 (biases to f32)
    detect_kernel<<<1, 256, 0, stream>>>(d_in[0], flag);
    cvt_bf16_kernel<<<(int)((nX + 255) / 256), 256, 0, stream>>>(d_in[0], xb,  (int)nX, flag);
    cvt_bf16_kernel<<<(int)((nW + 255) / 256), 256, 0, stream>>>(d_in[1], Wqb, (int)nW, flag);
    cvt_bf16_kernel<<<(int)((nW + 255) / 256), 256, 0, stream>>>(d_in[3], Wkb, (int)nW, flag);
    cvt_bf16_kernel<<<(int)((nW + 255) / 256), 256, 0, stream>>>(d_in[4], Wvb, (int)nW, flag);
    cvt_bf16_kernel<<<(int)((nW + 255) / 256), 256, 0, stream>>>(d_in[6], Wob, (int)nW, flag);
    cvt_f32_kernel<<<3, 256, 0, stream>>>(d_in[2], bqf, kD, flag);
    cvt_f32_kernel<<<3, 256, 0, stream>>>(d_in[5], bvf, kD, flag);
    cvt_f32_kernel<<<3, 256, 0, stream>>>(d_in[7], bof, kD, flag);

    // 2) fused QKV projection (+ padding): grid 94 x (3 mats * 6 n-blocks)
    zeropad_kernel<<<96, 256, 0, stream>>>(q_ws, k_ws, vt_ws);
    dim3 qkvgrid((kM + 127) / 128, 18);   // 94 x 18 = 1692 blocks
    qkv_kernel<<<qkvgrid, 256, 0, stream>>>(xb, Wqb, Wkb, Wvb, bqf, bvf,
                                            q_ws, k_ws, vt_ws);

    // 3) flash attention (1D grid: 12 q-blocks x 96 bh, bh fastest for XCD pin)
    fattn_kernel<<<dim3(12 * 96), 256, 0, stream>>>(q_ws, k_ws, vt_ws, ctx);

    // 4) output projection -> float32 d_out
    dim3 ogrid((kM + 127) / 128, kD / 128);   // 94 x 6
    out_kernel<<<ogrid, 256, 0, stream>>>(ctx, Wob, bof, out_f);
}

// Round 2
// 433.386 us; speedup vs baseline: 1.2060x; 1.0963x over previous
//
#include <hip/hip_runtime.h>
#include <hip/hip_bf16.h>

// Problem constants
constexpr int kD  = 768;
constexpr int kH  = 12;
constexpr int kDH = 64;
constexpr int kS  = 1500;
constexpr int kSP = 1504;        // S padded to multiple of 32 (47*32)
constexpr int kB  = 8;
constexpr int kM  = kB * kS;     // 12000 rows for the projections
constexpr float kScale = 0.125f;
constexpr int kPSTR = 72;        // P row stride (elems): 144B -> b64/b128 aligned

typedef __bf16 bf16;
typedef __bf16 bf16x4 __attribute__((ext_vector_type(4)));
typedef __bf16 bf16x8 __attribute__((ext_vector_type(8)));
typedef float  floatx4 __attribute__((ext_vector_type(4)));

// ---------------------------------------------------------------------------
// Dtype probe (round-1 NaN proved inputs are f32; cheap guard retained).
// ---------------------------------------------------------------------------
__global__ __launch_bounds__(256) void detect_kernel(const void* __restrict__ xraw,
                                                     int* __restrict__ flag) {
    __shared__ int bad;
    if (threadIdx.x == 0) bad = 0;
    __syncthreads();
    const bf16* xb = (const bf16*)xraw;
    int c = 0;
    for (int k = 0; k < 16; k++) {
        int idx = 2 * (threadIdx.x + 256 * k);
        float v = fabsf((float)xb[idx]);
        if (!(v == 0.0f || (v > 1e-20f && v < 1e6f))) c++;
    }
    atomicAdd(&bad, c);
    __syncthreads();
    if (threadIdx.x == 0) *flag = (bad > 8) ? 1 : 0;
}

__global__ __launch_bounds__(256) void cvt_bf16_kernel(const void* __restrict__ src,
                                                       bf16* __restrict__ dst, int n,
                                                       const int* __restrict__ flag) {
    int i = blockIdx.x * 256 + threadIdx.x;
    if (i < n) {
        if (*flag)
            dst[i] = (bf16)((const float*)src)[i];
        else
            dst[i] = ((const bf16*)src)[i];
    }
}

__global__ __launch_bounds__(256) void cvt_f32_kernel(const void* __restrict__ src,
                                                      float* __restrict__ dst, int n,
                                                      const int* __restrict__ flag) {
    int i = blockIdx.x * 256 + threadIdx.x;
    if (i < n) {
        if (*flag)
            dst[i] = ((const float*)src)[i];
        else
            dst[i] = (float)((const bf16*)src)[i];
    }
}

// ---------------------------------------------------------------------------
// Zero the S-padding rows of q/k and padding cols of v^T.
// ---------------------------------------------------------------------------
__global__ __launch_bounds__(256) void zeropad_kernel(bf16* __restrict__ q_ws,
                                                      bf16* __restrict__ k_ws,
                                                      bf16* __restrict__ vt_ws) {
    int t = blockIdx.x * 256 + threadIdx.x;          // 96 bh * 4 s * 64 dh = 24576
    if (t < kB * kH * (kSP - kS) * kDH) {
        int bh  = t >> 8;
        int rem = t & 255;
        int s   = kS + (rem >> 6);
        int dh  = rem & 63;
        size_t qi = ((size_t)bh * kSP + s) * kDH + dh;
        q_ws[qi] = (bf16)0.f;
        k_ws[qi] = (bf16)0.f;
        size_t vi = ((size_t)bh * kDH + dh) * kSP + s;
        vt_ws[vi] = (bf16)0.f;
    }
}

// ---------------------------------------------------------------------------
// m97-structure GEMM core (UNCHANGED this round): 128x128 tile, BK=32,
// 4 waves, 4x4 acc per wave, global_load_lds width-16 staging.
// ---------------------------------------------------------------------------
__device__ __forceinline__ void async_copy16(const bf16* g, bf16* l) {
    __builtin_amdgcn_global_load_lds(
        (const __attribute__((address_space(1))) void*)g,
        (__attribute__((address_space(3))) void*)l,
        16, 0, 0);
}

__device__ __forceinline__ void gemm128_core(const bf16* __restrict__ X,
                                             const bf16* __restrict__ W,
                                             int m0, int n0,
                                             bf16* Asm, bf16* Bsm,
                                             floatx4 acc[4][4]) {
    const int tid  = threadIdx.x;
    const int lane = tid & 63;
    const int w    = tid >> 6;
    const int srow = (w << 4) + (lane >> 2);
    const int scol = (lane & 3) << 3;
    const int lrow = lane & 15;
    const int lq   = lane >> 4;
    const int wm   = (w >> 1) << 6;
    const int wn   = (w & 1) << 6;

    const bf16* gA = X + (size_t)(m0 + srow) * kD + scol;
    const bf16* gB = W + (size_t)(n0 + srow) * kD + scol;
    bf16* lA = Asm + (w << 9);     // wave-uniform base; HW adds lane*16B
    bf16* lB = Bsm + (w << 9);

    for (int k0 = 0; k0 < kD; k0 += 32) {
        async_copy16(gA + k0, lA);
        async_copy16(gA + (size_t)64 * kD + k0, lA + 2048);
        async_copy16(gB + k0, lB);
        async_copy16(gB + (size_t)64 * kD + k0, lB + 2048);
        __syncthreads();

        bf16x8 af[4], bfr[4];
#pragma unroll
        for (int i = 0; i < 4; i++)
            af[i] = *(const bf16x8*)(Asm + ((wm + i * 16 + lrow) << 5) + (lq << 3));
#pragma unroll
        for (int j = 0; j < 4; j++)
            bfr[j] = *(const bf16x8*)(Bsm + ((wn + j * 16 + lrow) << 5) + (lq << 3));
#pragma unroll
        for (int i = 0; i < 4; i++)
#pragma unroll
            for (int j = 0; j < 4; j++)
                acc[i][j] = __builtin_amdgcn_mfma_f32_16x16x32_bf16(
                    af[i], bfr[j], acc[i][j], 0, 0, 0);
        __syncthreads();
    }
}

__global__ __launch_bounds__(256) void qkv_kernel(const bf16* __restrict__ X,
                                                  const bf16* __restrict__ Wq,
                                                  const bf16* __restrict__ Wk,
                                                  const bf16* __restrict__ Wv,
                                                  const float* __restrict__ bq,
                                                  const float* __restrict__ bv,
                                                  bf16* __restrict__ q_ws,
                                                  bf16* __restrict__ k_ws,
                                                  bf16* __restrict__ vt_ws) {
    __shared__ bf16 Asm[128 * 32];
    __shared__ bf16 Bsm[128 * 32];

    const int m0  = blockIdx.x << 7;
    const int mat = blockIdx.y / 6;
    const int n0  = (blockIdx.y % 6) << 7;
    const bf16* W = (mat == 0) ? Wq : (mat == 1) ? Wk : Wv;

    floatx4 acc[4][4] = {};
    gemm128_core(X, W, m0, n0, Asm, Bsm, acc);

    const int tid  = threadIdx.x;
    const int lane = tid & 63;
    const int w    = tid >> 6;
    const int lrow = lane & 15;
    const int lq   = lane >> 4;
    const int wm   = (w >> 1) << 6;
    const int wn   = (w & 1) << 6;

#pragma unroll
    for (int i = 0; i < 4; i++) {
#pragma unroll
        for (int j = 0; j < 4; j++) {
            const int n  = n0 + wn + j * 16 + lrow;
            const int hh = n >> 6, dh = n & 63;
            const float bval = (mat == 0) ? bq[n] : (mat == 2) ? bv[n] : 0.f;
#pragma unroll
            for (int r = 0; r < 4; r++) {
                const int m = m0 + wm + i * 16 + lq * 4 + r;
                if (m >= kM) continue;
                float v = acc[i][j][r];
                if (mat == 0)      v = (v + bval) * kScale;
                else if (mat == 2) v = v + bval;
                const int bb = m / kS, s = m - bb * kS;
                if (mat == 2)
                    vt_ws[(((size_t)(bb * kH + hh)) * kDH + dh) * kSP + s] = (bf16)v;
                else if (mat == 1)
                    k_ws[(((size_t)(bb * kH + hh)) * kSP + s) * kDH + dh] = (bf16)v;
                else
                    q_ws[(((size_t)(bb * kH + hh)) * kSP + s) * kDH + dh] = (bf16)v;
            }
        }
    }
}

__global__ __launch_bounds__(256) void out_kernel(const bf16* __restrict__ X,
                                                  const bf16* __restrict__ Wo,
                                                  const float* __restrict__ bo,
                                                  float* __restrict__ outf) {
    __shared__ bf16 Asm[128 * 32];
    __shared__ bf16 Bsm[128 * 32];

    const int m0 = blockIdx.x << 7;
    const int n0 = blockIdx.y << 7;

    floatx4 acc[4][4] = {};
    gemm128_core(X, Wo, m0, n0, Asm, Bsm, acc);

    const int tid  = threadIdx.x;
    const int lane = tid & 63;
    const int w    = tid >> 6;
    const int lrow = lane & 15;
    const int lq   = lane >> 4;
    const int wm   = (w >> 1) << 6;
    const int wn   = (w & 1) << 6;

#pragma unroll
    for (int i = 0; i < 4; i++) {
#pragma unroll
        for (int j = 0; j < 4; j++) {
            const int n = n0 + wn + j * 16 + lrow;
            const float bval = bo[n];
#pragma unroll
            for (int r = 0; r < 4; r++) {
                const int m = m0 + wm + i * 16 + lq * 4 + r;
                if (m >= kM) continue;
                outf[(size_t)m * kD + n] = acc[i][j][r] + bval;
            }
        }
    }
}

// ---------------------------------------------------------------------------
// Flash attention v5: same dataflow as v4 (transposed QK, no-max softmax,
// P through per-wave LDS slice, V^T K=32 PV, 2 Q-tiles/wave) but explicitly
// software-pipelined in registers:
//   - K fragments for chunk i+1 issued during chunk i's PV phase
//     (register double-buffer, all indices compile-time).
//   - All 8 V fragments for chunk i issued BEFORE the QK/exp/P-write phase,
//     hiding their latency under it.
//   - s_setprio(1) around MFMA clusters.
// VGPR target ~200 (launch_bounds(256,2) caps at 256): trades TLP (measured
// occupancy was only 8.3 waves/CU anyway) for in-wave ILP.
// ---------------------------------------------------------------------------
__device__ __forceinline__ void load_k4(const bf16* __restrict__ kbase, int s0,
                                        int col, int quad, bf16x8 kf[4][2]) {
#pragma unroll
    for (int t = 0; t < 4; t++) {
        const bf16* kr = kbase + (size_t)(s0 + 16 * t + col) * kDH + quad * 8;
        kf[t][0] = *(const bf16x8*)(kr);
        kf[t][1] = *(const bf16x8*)(kr + 32);
    }
}

__device__ __forceinline__ void load_k2(const bf16* __restrict__ kbase, int s0,
                                        int col, int quad, bf16x8 kf[4][2]) {
#pragma unroll
    for (int t = 0; t < 2; t++) {
        const bf16* kr = kbase + (size_t)(s0 + 16 * t + col) * kDH + quad * 8;
        kf[t][0] = *(const bf16x8*)(kr);
        kf[t][1] = *(const bf16x8*)(kr + 32);
    }
}

template <int NT>
__device__ __forceinline__ void load_v(const bf16* __restrict__ vbase, int s0,
                                       int col, int quad, bf16x8 vf[4][2]) {
#pragma unroll
    for (int n = 0; n < 4; n++) {
        const bf16* vr = vbase + (size_t)(n * 16 + col) * kSP + s0 + quad * 8;
#pragma unroll
        for (int kc = 0; kc < NT / 2; kc++)
            vf[n][kc] = *(const bf16x8*)(vr + kc * 32);
    }
}

template <int NT, bool MASK>
__device__ __forceinline__ void qk_phase(const bf16x8 kf[4][2],
                                         const bf16x8 qf[2][2],
                                         bf16* __restrict__ P,
                                         float lsum[2],
                                         int s0, int col, int quad) {
#pragma unroll
    for (int t = 0; t < NT; t++) {
#pragma unroll
        for (int qt = 0; qt < 2; qt++) {
            floatx4 sc = {0.f, 0.f, 0.f, 0.f};
            __builtin_amdgcn_s_setprio(1);
            sc = __builtin_amdgcn_mfma_f32_16x16x32_bf16(kf[t][0], qf[qt][0], sc, 0, 0, 0);
            sc = __builtin_amdgcn_mfma_f32_16x16x32_bf16(kf[t][1], qf[qt][1], sc, 0, 0, 0);
            __builtin_amdgcn_s_setprio(0);
            bf16x4 pv;
#pragma unroll
            for (int r = 0; r < 4; r++) {
                float p;
                if (MASK && (s0 + 16 * t + quad * 4 + r >= kS))
                    p = 0.f;
                else
                    p = __expf(sc[r]);
                lsum[qt] += p;
                pv[r] = (bf16)p;
            }
            *(bf16x4*)(P + (qt * 16 + col) * kPSTR + 16 * t + quad * 4) = pv;
        }
    }
}

template <int NT>
__device__ __forceinline__ void pv_phase(const bf16x8 vf[4][2],
                                         const bf16* __restrict__ P,
                                         floatx4 Oacc[2][4],
                                         int col, int quad) {
    constexpr int KC = NT / 2;
    bf16x8 pa[2][2];
#pragma unroll
    for (int qt = 0; qt < 2; qt++)
#pragma unroll
        for (int kc = 0; kc < KC; kc++)
            pa[qt][kc] = *(const bf16x8*)(P + (qt * 16 + col) * kPSTR + kc * 32 + quad * 8);
    __builtin_amdgcn_s_setprio(1);
#pragma unroll
    for (int n = 0; n < 4; n++)
#pragma unroll
        for (int kc = 0; kc < KC; kc++)
#pragma unroll
            for (int qt = 0; qt < 2; qt++)
                Oacc[qt][n] = __builtin_amdgcn_mfma_f32_16x16x32_bf16(
                    pa[qt][kc], vf[n][kc], Oacc[qt][n], 0, 0, 0);
    __builtin_amdgcn_s_setprio(0);
}

__global__ __launch_bounds__(256, 2) void fattn_kernel(const bf16* __restrict__ q_ws,
                                                       const bf16* __restrict__ k_ws,
                                                       const bf16* __restrict__ vt_ws,
                                                       bf16* __restrict__ ctx) {
    __shared__ bf16 Pbuf[4][32 * kPSTR];   // 18432 B, per-wave slices

    const int idx = blockIdx.x;         // 0..1151; bh fastest -> idx%8 = bh%8 (XCD)
    const int bh  = idx % 96;
    const int qb  = idx / 96;           // 0..11, 128 Q rows per block
    const int b   = bh / kH;
    const int h   = bh - b * kH;
    const int tid  = threadIdx.x;
    const int w    = tid >> 6;
    const int lane = tid & 63;
    const int col  = lane & 15;         // q index within a 16-row tile
    const int quad = lane >> 4;
    const int q0   = qb * 128 + w * 32; // this wave's 32 Q rows (2 tiles)
    if (q0 >= kS) return;               // no barriers below: divergent exit OK

    const bf16* qbase = q_ws  + (size_t)bh * kSP * kDH;
    const bf16* kbase = k_ws  + (size_t)bh * kSP * kDH;
    const bf16* vbase = vt_ws + (size_t)bh * kDH * kSP;

    bf16x8 qf[2][2];
#pragma unroll
    for (int qt = 0; qt < 2; qt++) {
        const bf16* qr = qbase + (size_t)(q0 + qt * 16 + col) * kDH + quad * 8;
        qf[qt][0] = *(const bf16x8*)(qr);
        qf[qt][1] = *(const bf16x8*)(qr + 32);
    }

    float lsum[2] = {0.f, 0.f};
    floatx4 Oacc[2][4];
#pragma unroll
    for (int qt = 0; qt < 2; qt++)
#pragma unroll
        for (int n = 0; n < 4; n++) Oacc[qt][n] = (floatx4){0.f, 0.f, 0.f, 0.f};

    bf16* P = &Pbuf[w][0];

    // Software-pipelined key loop: 24 chunks total
    //   chunks 0..21  : full 64-key, K for chunk i+1 prefetched during PV(i)
    //   chunk 22      : full 64-key at s0=1408, prefetches the 32-key tail
    //   chunk 23      : masked 32-key tail at s0=1472
    bf16x8 kcur[4][2], knxt[4][2], vcur[4][2];
    load_k4(kbase, 0, col, quad, kcur);

    for (int s0 = 0; s0 < 1408; s0 += 64) {
        load_v<4>(vbase, s0, col, quad, vcur);
        qk_phase<4, false>(kcur, qf, P, lsum, s0, col, quad);
        load_k4(kbase, s0 + 64, col, quad, knxt);
        pv_phase<4>(vcur, P, Oacc, col, quad);
#pragma unroll
        for (int t = 0; t < 4; t++) {
            kcur[t][0] = knxt[t][0];
            kcur[t][1] = knxt[t][1];
        }
    }

    // chunk 22 (s0 = 1408)
    load_v<4>(vbase, 1408, col, quad, vcur);
    qk_phase<4, false>(kcur, qf, P, lsum, 1408, col, quad);
    load_k2(kbase, 1472, col, quad, knxt);
    pv_phase<4>(vcur, P, Oacc, col, quad);

    // chunk 23 (s0 = 1472, 32 keys, masked)
    load_v<2>(vbase, 1472, col, quad, vcur);
    qk_phase<2, true>(knxt, qf, P, lsum, 1472, col, quad);
    pv_phase<2>(vcur, P, Oacc, col, quad);

#pragma unroll
    for (int qt = 0; qt < 2; qt++) {
        float l = lsum[qt];
        l += __shfl_xor(l, 16);
        l += __shfl_xor(l, 32);
        const float rinv_col = 1.0f / l;             // for q = col of this tile
        float ri[4];
#pragma unroll
        for (int r = 0; r < 4; r++)
            ri[r] = __shfl(rinv_col, quad * 4 + r, 16);
#pragma unroll
        for (int n = 0; n < 4; n++)
#pragma unroll
            for (int r = 0; r < 4; r++) {
                const int q = q0 + qt * 16 + quad * 4 + r;
                if (q < kS)
                    ctx[((size_t)(b * kS + q)) * kD + h * kDH + n * 16 + col] =
                        (bf16)(Oacc[qt][n][r] * ri[r]);
            }
    }
}

// ---------------------------------------------------------------------------
extern "C" void kernel_launch(void* const* d_in, const int* in_sizes, int n_in,
                              void* d_out, int out_size, void* d_ws, size_t ws_size,
                              hipStream_t stream) {
    float* out_f = (float*)d_out;   // reference output dtype is float32

    constexpr size_t nX = (size_t)kM * kD;
    constexpr size_t nW = (size_t)kD * kD;
    constexpr size_t per_qkv = (size_t)kB * kH * kSP * kDH;

    bf16* xb    = (bf16*)d_ws;
    bf16* Wqb   = xb + nX;
    bf16* Wkb   = Wqb + nW;
    bf16* Wvb   = Wkb + nW;
    bf16* Wob   = Wvb + nW;
    bf16* q_ws  = Wob + nW;
    bf16* k_ws  = q_ws + per_qkv;
    bf16* vt_ws = k_ws + per_qkv;
    float* bqf  = (float*)(vt_ws + per_qkv);
    float* bvf  = bqf + kD;
    float* bof  = bvf + kD;
    int*  flag  = (int*)(bof + kD);
    bf16* ctx   = xb;   // alias: xb last read by qkv_kernel, ctx written after

    // 1) dtype probe + input normalization to bf16 (biases to f32)
    detect_kernel<<<1, 256, 0, stream>>>(d_in[0], flag);
    cvt_bf16_kernel<<<(int)((nX + 255) / 256), 256, 0, stream>>>(d_in[0], xb,  (int)nX, flag);
    cvt_bf16_kernel<<<(int)((nW + 255) / 256), 256, 0, stream>>>(d_in[1], Wqb, (int)nW, flag);
    cvt_bf16_kernel<<<(int)((nW + 255) / 256), 256, 0, stream>>>(d_in[3], Wkb, (int)nW, flag);
    cvt_bf16_kernel<<<(int)((nW + 255) / 256), 256, 0, stream>>>(d_in[4], Wvb, (int)nW, flag);
    cvt_bf16_kernel<<<(int)((nW + 255) / 256), 256, 0, stream>>>(d_in[6], Wob, (int)nW, flag);
    cvt_f32_kernel<<<3, 256, 0, stream>>>(d_in[2], bqf, kD, flag);
    cvt_f32_kernel<<<3, 256, 0, stream>>>(d_in[5], bvf, kD, flag);
    cvt_f32_kernel<<<3, 256, 0, stream>>>(d_in[7], bof, kD, flag);

    // 2) fused QKV projection (+ padding): grid 94 x (3 mats * 6 n-blocks)
    zeropad_kernel<<<96, 256, 0, stream>>>(q_ws, k_ws, vt_ws);
    dim3 qkvgrid((kM + 127) / 128, 18);   // 94 x 18 = 1692 blocks
    qkv_kernel<<<qkvgrid, 256, 0, stream>>>(xb, Wqb, Wkb, Wvb, bqf, bvf,
                                            q_ws, k_ws, vt_ws);

    // 3) flash attention (1D grid: 12 q-blocks x 96 bh, bh fastest for XCD pin)
    fattn_kernel<<<dim3(12 * 96), 256, 0, stream>>>(q_ws, k_ws, vt_ws, ctx);

    // 4) output projection -> float32 d_out
    dim3 ogrid((kM + 127) / 128, kD / 128);   // 94 x 6
    out_kernel<<<ogrid, 256, 0, stream>>>(ctx, Wob, bof, out_f);
}

// Round 3
// 430.874 us; speedup vs baseline: 1.2130x; 1.0058x over previous
//
#include <hip/hip_runtime.h>
#include <hip/hip_bf16.h>

// Problem constants
constexpr int kD  = 768;
constexpr int kH  = 12;
constexpr int kDH = 64;
constexpr int kS  = 1500;
constexpr int kSP = 1504;        // S padded to multiple of 32 (47*32)
constexpr int kB  = 8;
constexpr int kM  = kB * kS;     // 12000 rows for the projections
constexpr float kScale = 0.125f;
constexpr int kPSTR = 72;        // P row stride (elems): 144B -> b64/b128 aligned
constexpr int kPHALF = 32 * kPSTR;   // one P buffer half per wave

typedef __bf16 bf16;
typedef __bf16 bf16x4 __attribute__((ext_vector_type(4)));
typedef __bf16 bf16x8 __attribute__((ext_vector_type(8)));
typedef float  floatx4 __attribute__((ext_vector_type(4)));

// ---------------------------------------------------------------------------
// Dtype probe (round-1 NaN proved inputs are f32; cheap guard retained).
// ---------------------------------------------------------------------------
__global__ __launch_bounds__(256) void detect_kernel(const void* __restrict__ xraw,
                                                     int* __restrict__ flag) {
    __shared__ int bad;
    if (threadIdx.x == 0) bad = 0;
    __syncthreads();
    const bf16* xb = (const bf16*)xraw;
    int c = 0;
    for (int k = 0; k < 16; k++) {
        int idx = 2 * (threadIdx.x + 256 * k);
        float v = fabsf((float)xb[idx]);
        if (!(v == 0.0f || (v > 1e-20f && v < 1e6f))) c++;
    }
    atomicAdd(&bad, c);
    __syncthreads();
    if (threadIdx.x == 0) *flag = (bad > 8) ? 1 : 0;
}

__global__ __launch_bounds__(256) void cvt_bf16_kernel(const void* __restrict__ src,
                                                       bf16* __restrict__ dst, int n,
                                                       const int* __restrict__ flag) {
    int i = blockIdx.x * 256 + threadIdx.x;
    if (i < n) {
        if (*flag)
            dst[i] = (bf16)((const float*)src)[i];
        else
            dst[i] = ((const bf16*)src)[i];
    }
}

__global__ __launch_bounds__(256) void cvt_f32_kernel(const void* __restrict__ src,
                                                      float* __restrict__ dst, int n,
                                                      const int* __restrict__ flag) {
    int i = blockIdx.x * 256 + threadIdx.x;
    if (i < n) {
        if (*flag)
            dst[i] = ((const float*)src)[i];
        else
            dst[i] = (float)((const bf16*)src)[i];
    }
}

// ---------------------------------------------------------------------------
// Zero the S-padding rows of q/k and padding cols of v^T.
// ---------------------------------------------------------------------------
__global__ __launch_bounds__(256) void zeropad_kernel(bf16* __restrict__ q_ws,
                                                      bf16* __restrict__ k_ws,
                                                      bf16* __restrict__ vt_ws) {
    int t = blockIdx.x * 256 + threadIdx.x;          // 96 bh * 4 s * 64 dh = 24576
    if (t < kB * kH * (kSP - kS) * kDH) {
        int bh  = t >> 8;
        int rem = t & 255;
        int s   = kS + (rem >> 6);
        int dh  = rem & 63;
        size_t qi = ((size_t)bh * kSP + s) * kDH + dh;
        q_ws[qi] = (bf16)0.f;
        k_ws[qi] = (bf16)0.f;
        size_t vi = ((size_t)bh * kDH + dh) * kSP + s;
        vt_ws[vi] = (bf16)0.f;
    }
}

// ---------------------------------------------------------------------------
// m97-structure GEMM core (UNCHANGED): 128x128 tile, BK=32, 4 waves,
// 4x4 acc per wave, global_load_lds width-16 staging.
// ---------------------------------------------------------------------------
__device__ __forceinline__ void async_copy16(const bf16* g, bf16* l) {
    __builtin_amdgcn_global_load_lds(
        (const __attribute__((address_space(1))) void*)g,
        (__attribute__((address_space(3))) void*)l,
        16, 0, 0);
}

__device__ __forceinline__ void gemm128_core(const bf16* __restrict__ X,
                                             const bf16* __restrict__ W,
                                             int m0, int n0,
                                             bf16* Asm, bf16* Bsm,
                                             floatx4 acc[4][4]) {
    const int tid  = threadIdx.x;
    const int lane = tid & 63;
    const int w    = tid >> 6;
    const int srow = (w << 4) + (lane >> 2);
    const int scol = (lane & 3) << 3;
    const int lrow = lane & 15;
    const int lq   = lane >> 4;
    const int wm   = (w >> 1) << 6;
    const int wn   = (w & 1) << 6;

    const bf16* gA = X + (size_t)(m0 + srow) * kD + scol;
    const bf16* gB = W + (size_t)(n0 + srow) * kD + scol;
    bf16* lA = Asm + (w << 9);     // wave-uniform base; HW adds lane*16B
    bf16* lB = Bsm + (w << 9);

    for (int k0 = 0; k0 < kD; k0 += 32) {
        async_copy16(gA + k0, lA);
        async_copy16(gA + (size_t)64 * kD + k0, lA + 2048);
        async_copy16(gB + k0, lB);
        async_copy16(gB + (size_t)64 * kD + k0, lB + 2048);
        __syncthreads();

        bf16x8 af[4], bfr[4];
#pragma unroll
        for (int i = 0; i < 4; i++)
            af[i] = *(const bf16x8*)(Asm + ((wm + i * 16 + lrow) << 5) + (lq << 3));
#pragma unroll
        for (int j = 0; j < 4; j++)
            bfr[j] = *(const bf16x8*)(Bsm + ((wn + j * 16 + lrow) << 5) + (lq << 3));
#pragma unroll
        for (int i = 0; i < 4; i++)
#pragma unroll
            for (int j = 0; j < 4; j++)
                acc[i][j] = __builtin_amdgcn_mfma_f32_16x16x32_bf16(
                    af[i], bfr[j], acc[i][j], 0, 0, 0);
        __syncthreads();
    }
}

__global__ __launch_bounds__(256) void qkv_kernel(const bf16* __restrict__ X,
                                                  const bf16* __restrict__ Wq,
                                                  const bf16* __restrict__ Wk,
                                                  const bf16* __restrict__ Wv,
                                                  const float* __restrict__ bq,
                                                  const float* __restrict__ bv,
                                                  bf16* __restrict__ q_ws,
                                                  bf16* __restrict__ k_ws,
                                                  bf16* __restrict__ vt_ws) {
    __shared__ bf16 Asm[128 * 32];
    __shared__ bf16 Bsm[128 * 32];

    const int m0  = blockIdx.x << 7;
    const int mat = blockIdx.y / 6;
    const int n0  = (blockIdx.y % 6) << 7;
    const bf16* W = (mat == 0) ? Wq : (mat == 1) ? Wk : Wv;

    floatx4 acc[4][4] = {};
    gemm128_core(X, W, m0, n0, Asm, Bsm, acc);

    const int tid  = threadIdx.x;
    const int lane = tid & 63;
    const int w    = tid >> 6;
    const int lrow = lane & 15;
    const int lq   = lane >> 4;
    const int wm   = (w >> 1) << 6;
    const int wn   = (w & 1) << 6;

#pragma unroll
    for (int i = 0; i < 4; i++) {
#pragma unroll
        for (int j = 0; j < 4; j++) {
            const int n  = n0 + wn + j * 16 + lrow;
            const int hh = n >> 6, dh = n & 63;
            const float bval = (mat == 0) ? bq[n] : (mat == 2) ? bv[n] : 0.f;
#pragma unroll
            for (int r = 0; r < 4; r++) {
                const int m = m0 + wm + i * 16 + lq * 4 + r;
                if (m >= kM) continue;
                float v = acc[i][j][r];
                if (mat == 0)      v = (v + bval) * kScale;
                else if (mat == 2) v = v + bval;
                const int bb = m / kS, s = m - bb * kS;
                if (mat == 2)
                    vt_ws[(((size_t)(bb * kH + hh)) * kDH + dh) * kSP + s] = (bf16)v;
                else if (mat == 1)
                    k_ws[(((size_t)(bb * kH + hh)) * kSP + s) * kDH + dh] = (bf16)v;
                else
                    q_ws[(((size_t)(bb * kH + hh)) * kSP + s) * kDH + dh] = (bf16)v;
            }
        }
    }
}

__global__ __launch_bounds__(256) void out_kernel(const bf16* __restrict__ X,
                                                  const bf16* __restrict__ Wo,
                                                  const float* __restrict__ bo,
                                                  float* __restrict__ outf) {
    __shared__ bf16 Asm[128 * 32];
    __shared__ bf16 Bsm[128 * 32];

    const int m0 = blockIdx.x << 7;
    const int n0 = blockIdx.y << 7;

    floatx4 acc[4][4] = {};
    gemm128_core(X, Wo, m0, n0, Asm, Bsm, acc);

    const int tid  = threadIdx.x;
    const int lane = tid & 63;
    const int w    = tid >> 6;
    const int lrow = lane & 15;
    const int lq   = lane >> 4;
    const int wm   = (w >> 1) << 6;
    const int wn   = (w & 1) << 6;

#pragma unroll
    for (int i = 0; i < 4; i++) {
#pragma unroll
        for (int j = 0; j < 4; j++) {
            const int n = n0 + wn + j * 16 + lrow;
            const float bval = bo[n];
#pragma unroll
            for (int r = 0; r < 4; r++) {
                const int m = m0 + wm + i * 16 + lq * 4 + r;
                if (m >= kM) continue;
                outf[(size_t)m * kD + n] = acc[i][j][r] + bval;
            }
        }
    }
}

// ---------------------------------------------------------------------------
// Flash attention v6: T15 two-chunk pipeline. Iteration c executes
//   QK(c) -> prefetch K(c+1) -> PV(c-1) -> prefetch V(c) -> exp(c)+Pwrite(c)
// so PV(c-1)'s 16 MFMAs overlap QK(c)'s result latency, the P LDS
// write->read distance spans a whole QK phase (double-buffered halves),
// and all K/V loads hide under compute. sc held in registers (32 VGPR).
// Tail: chunk 23 runs as a full masked 64-key chunk for QK/exp (garbage K
// rows confine to their own C rows; masked keys store exact 0), PV tail
// uses only the in-bounds 32 keys.
// ---------------------------------------------------------------------------
__device__ __forceinline__ void load_k4(const bf16* __restrict__ kbase, int s0,
                                        int col, int quad, bf16x8 kf[4][2]) {
#pragma unroll
    for (int t = 0; t < 4; t++) {
        const bf16* kr = kbase + (size_t)(s0 + 16 * t + col) * kDH + quad * 8;
        kf[t][0] = *(const bf16x8*)(kr);
        kf[t][1] = *(const bf16x8*)(kr + 32);
    }
}

template <int NT>
__device__ __forceinline__ void load_v(const bf16* __restrict__ vbase, int s0,
                                       int col, int quad, bf16x8 vf[4][2]) {
#pragma unroll
    for (int n = 0; n < 4; n++) {
        const bf16* vr = vbase + (size_t)(n * 16 + col) * kSP + s0 + quad * 8;
#pragma unroll
        for (int kc = 0; kc < NT / 2; kc++)
            vf[n][kc] = *(const bf16x8*)(vr + kc * 32);
    }
}

__device__ __forceinline__ void qk_mfma(const bf16x8 kf[4][2],
                                        const bf16x8 qf[2][2],
                                        floatx4 sc[2][4]) {
    __builtin_amdgcn_s_setprio(1);
#pragma unroll
    for (int t = 0; t < 4; t++)
#pragma unroll
        for (int qt = 0; qt < 2; qt++) {
            floatx4 a = {0.f, 0.f, 0.f, 0.f};
            a = __builtin_amdgcn_mfma_f32_16x16x32_bf16(kf[t][0], qf[qt][0], a, 0, 0, 0);
            a = __builtin_amdgcn_mfma_f32_16x16x32_bf16(kf[t][1], qf[qt][1], a, 0, 0, 0);
            sc[qt][t] = a;
        }
    __builtin_amdgcn_s_setprio(0);
}

template <bool MASK>
__device__ __forceinline__ void exp_store(const floatx4 sc[2][4],
                                          bf16* __restrict__ Pw,
                                          float lsum[2],
                                          int s0, int col, int quad) {
#pragma unroll
    for (int qt = 0; qt < 2; qt++)
#pragma unroll
        for (int t = 0; t < 4; t++) {
            bf16x4 pv;
#pragma unroll
            for (int r = 0; r < 4; r++) {
                float p;
                if (MASK && (s0 + 16 * t + quad * 4 + r >= kS))
                    p = 0.f;
                else
                    p = __expf(sc[qt][t][r]);
                lsum[qt] += p;
                pv[r] = (bf16)p;
            }
            *(bf16x4*)(Pw + (qt * 16 + col) * kPSTR + 16 * t + quad * 4) = pv;
        }
}

template <int NT>
__device__ __forceinline__ void pv_phase(const bf16x8 vf[4][2],
                                         const bf16* __restrict__ Pr,
                                         floatx4 Oacc[2][4],
                                         int col, int quad) {
    constexpr int KC = NT / 2;
    bf16x8 pa[2][2];
#pragma unroll
    for (int qt = 0; qt < 2; qt++)
#pragma unroll
        for (int kc = 0; kc < KC; kc++)
            pa[qt][kc] = *(const bf16x8*)(Pr + (qt * 16 + col) * kPSTR + kc * 32 + quad * 8);
    __builtin_amdgcn_s_setprio(1);
#pragma unroll
    for (int n = 0; n < 4; n++)
#pragma unroll
        for (int kc = 0; kc < KC; kc++)
#pragma unroll
            for (int qt = 0; qt < 2; qt++)
                Oacc[qt][n] = __builtin_amdgcn_mfma_f32_16x16x32_bf16(
                    pa[qt][kc], vf[n][kc], Oacc[qt][n], 0, 0, 0);
    __builtin_amdgcn_s_setprio(0);
}

__global__ __launch_bounds__(256, 2) void fattn_kernel(const bf16* __restrict__ q_ws,
                                                       const bf16* __restrict__ k_ws,
                                                       const bf16* __restrict__ vt_ws,
                                                       bf16* __restrict__ ctx) {
    __shared__ bf16 Pbuf[4][2][kPHALF];   // 36864 B: per-wave double-buffered P

    const int idx = blockIdx.x;         // 0..1151; bh fastest -> idx%8 = bh%8 (XCD)
    const int bh  = idx % 96;
    const int qb  = idx / 96;           // 0..11, 128 Q rows per block
    const int b   = bh / kH;
    const int h   = bh - b * kH;
    const int tid  = threadIdx.x;
    const int w    = tid >> 6;
    const int lane = tid & 63;
    const int col  = lane & 15;         // q index within a 16-row tile
    const int quad = lane >> 4;
    const int q0   = qb * 128 + w * 32; // this wave's 32 Q rows (2 tiles)
    if (q0 >= kS) return;               // no barriers below: divergent exit OK

    const bf16* qbase = q_ws  + (size_t)bh * kSP * kDH;
    const bf16* kbase = k_ws  + (size_t)bh * kSP * kDH;
    const bf16* vbase = vt_ws + (size_t)bh * kDH * kSP;

    bf16x8 qf[2][2];
#pragma unroll
    for (int qt = 0; qt < 2; qt++) {
        const bf16* qr = qbase + (size_t)(q0 + qt * 16 + col) * kDH + quad * 8;
        qf[qt][0] = *(const bf16x8*)(qr);
        qf[qt][1] = *(const bf16x8*)(qr + 32);
    }

    float lsum[2] = {0.f, 0.f};
    floatx4 Oacc[2][4];
#pragma unroll
    for (int qt = 0; qt < 2; qt++)
#pragma unroll
        for (int n = 0; n < 4; n++) Oacc[qt][n] = (floatx4){0.f, 0.f, 0.f, 0.f};

    bf16* const P0 = &Pbuf[w][0][0];
    bf16* const P1 = &Pbuf[w][1][0];

    bf16x8 kf[4][2], vf[4][2];
    floatx4 sc[2][4];

    // ---- prologue: chunk 0 ----
    load_k4(kbase, 0, col, quad, kf);
    load_v<4>(vbase, 0, col, quad, vf);      // V(0), consumed by PV(0) in iter 1
    qk_mfma(kf, qf, sc);                     // QK(0)
    load_k4(kbase, 64, col, quad, kf);       // K(1)
    exp_store<false>(sc, P0, lsum, 0, col, quad);   // P(0) -> half 0

    // ---- steady state: c = 1..22 (all full 64-key chunks) ----
    for (int c = 1; c < 23; ++c) {
        const int s0 = c * 64;
        bf16* Pw = (c & 1) ? P1 : P0;
        const bf16* Pr = (c & 1) ? P0 : P1;
        qk_mfma(kf, qf, sc);                 // QK(c)
        load_k4(kbase, s0 + 64, col, quad, kf);   // K(c+1); c=22 loads tail (garbage top rows OK)
        pv_phase<4>(vf, Pr, Oacc, col, quad);     // PV(c-1) with V(c-1)
        load_v<4>(vbase, s0, col, quad, vf);      // V(c)
        exp_store<false>(sc, Pw, lsum, s0, col, quad);
    }

    // ---- iter 23: masked QK tail + PV(22) ----
    qk_mfma(kf, qf, sc);                     // QK(23), keys 1472..1535 (top garbage)
    pv_phase<4>(vf, P0, Oacc, col, quad);    // PV(22) reads half 0 (22 even)
    load_v<2>(vbase, 1472, col, quad, vf);   // V(23): in-bounds 32 keys only
    exp_store<true>(sc, P1, lsum, 1472, col, quad);  // P(23) -> half 1, masked

    // ---- epilogue: PV(23) over 32 in-bounds keys ----
    pv_phase<2>(vf, P1, Oacc, col, quad);

#pragma unroll
    for (int qt = 0; qt < 2; qt++) {
        float l = lsum[qt];
        l += __shfl_xor(l, 16);
        l += __shfl_xor(l, 32);
        const float rinv_col = 1.0f / l;             // for q = col of this tile
        float ri[4];
#pragma unroll
        for (int r = 0; r < 4; r++)
            ri[r] = __shfl(rinv_col, quad * 4 + r, 16);
#pragma unroll
        for (int n = 0; n < 4; n++)
#pragma unroll
            for (int r = 0; r < 4; r++) {
                const int q = q0 + qt * 16 + quad * 4 + r;
                if (q < kS)
                    ctx[((size_t)(b * kS + q)) * kD + h * kDH + n * 16 + col] =
                        (bf16)(Oacc[qt][n][r] * ri[r]);
            }
    }
}

// ---------------------------------------------------------------------------
extern "C" void kernel_launch(void* const* d_in, const int* in_sizes, int n_in,
                              void* d_out, int out_size, void* d_ws, size_t ws_size,
                              hipStream_t stream) {
    float* out_f = (float*)d_out;   // reference output dtype is float32

    constexpr size_t nX = (size_t)kM * kD;
    constexpr size_t nW = (size_t)kD * kD;
    constexpr size_t per_qkv = (size_t)kB * kH * kSP * kDH;

    bf16* xb    = (bf16*)d_ws;
    bf16* Wqb   = xb + nX;
    bf16* Wkb   = Wqb + nW;
    bf16* Wvb   = Wkb + nW;
    bf16* Wob   = Wvb + nW;
    bf16* q_ws  = Wob + nW;
    bf16* k_ws  = q_ws + per_qkv;
    bf16* vt_ws = k_ws + per_qkv;
    float* bqf  = (float*)(vt_ws + per_qkv);
    float* bvf  = bqf + kD;
    float* bof  = bvf + kD;
    int*  flag  = (int*)(bof + kD);
    bf16* ctx   = xb;   // alias: xb last read by qkv_kernel, ctx written after

    // 1) dtype probe + input normalization to bf16 (biases to f32)
    detect_kernel<<<1, 256, 0, stream>>>(d_in[0], flag);
    cvt_bf16_kernel<<<(int)((nX + 255) / 256), 256, 0, stream>>>(d_in[0], xb,  (int)nX, flag);
    cvt_bf16_kernel<<<(int)((nW + 255) / 256), 256, 0, stream>>>(d_in[1], Wqb, (int)nW, flag);
    cvt_bf16_kernel<<<(int)((nW + 255) / 256), 256, 0, stream>>>(d_in[3], Wkb, (int)nW, flag);
    cvt_bf16_kernel<<<(int)((nW + 255) / 256), 256, 0, stream>>>(d_in[4], Wvb, (int)nW, flag);
    cvt_bf16_kernel<<<(int)((nW + 255) / 256), 256, 0, stream>>>(d_in[6], Wob, (int)nW, flag);
    cvt_f32_kernel<<<3, 256, 0, stream>>>(d_in[2], bqf, kD, flag);
    cvt_f32_kernel<<<3, 256, 0, stream>>>(d_in[5], bvf, kD, flag);
    cvt_f32_kernel<<<3, 256, 0, stream>>>(d_in[7], bof, kD, flag);

    // 2) fused QKV projection (+ padding): grid 94 x (3 mats * 6 n-blocks)
    zeropad_kernel<<<96, 256, 0, stream>>>(q_ws, k_ws, vt_ws);
    dim3 qkvgrid((kM + 127) / 128, 18);   // 94 x 18 = 1692 blocks
    qkv_kernel<<<qkvgrid, 256, 0, stream>>>(xb, Wqb, Wkb, Wvb, bqf, bvf,
                                            q_ws, k_ws, vt_ws);

    // 3) flash attention (1D grid: 12 q-blocks x 96 bh, bh fastest for XCD pin)
    fattn_kernel<<<dim3(12 * 96), 256, 0, stream>>>(q_ws, k_ws, vt_ws, ctx);

    // 4) output projection -> float32 d_out
    dim3 ogrid((kM + 127) / 128, kD / 128);   // 94 x 6
    out_kernel<<<ogrid, 256, 0, stream>>>(ctx, Wob, bof, out_f);
}

// Round 4
// 351.884 us; speedup vs baseline: 1.4853x; 1.2245x over previous
//
#include <hip/hip_runtime.h>
#include <hip/hip_bf16.h>

// Problem constants
constexpr int kD  = 768;
constexpr int kH  = 12;
constexpr int kDH = 64;
constexpr int kS  = 1500;
constexpr int kSP = 1504;        // S padded to multiple of 32 (47*32)
constexpr int kB  = 8;
constexpr int kM  = kB * kS;     // 12000 rows for the projections
constexpr float kScale = 0.125f;
constexpr int kPSTR = 72;        // P row stride (elems): 144B -> b64/b128 aligned

typedef __bf16 bf16;
typedef __bf16 bf16x4 __attribute__((ext_vector_type(4)));
typedef __bf16 bf16x8 __attribute__((ext_vector_type(8)));
typedef float  floatx4 __attribute__((ext_vector_type(4)));

// ---------------------------------------------------------------------------
// Dtype probe (round-1 NaN proved inputs are f32; cheap guard retained).
// ---------------------------------------------------------------------------
__global__ __launch_bounds__(256) void detect_kernel(const void* __restrict__ xraw,
                                                     int* __restrict__ flag) {
    __shared__ int bad;
    if (threadIdx.x == 0) bad = 0;
    __syncthreads();
    const bf16* xb = (const bf16*)xraw;
    int c = 0;
    for (int k = 0; k < 16; k++) {
        int idx = 2 * (threadIdx.x + 256 * k);
        float v = fabsf((float)xb[idx]);
        if (!(v == 0.0f || (v > 1e-20f && v < 1e6f))) c++;
    }
    atomicAdd(&bad, c);
    __syncthreads();
    if (threadIdx.x == 0) *flag = (bad > 8) ? 1 : 0;
}

__global__ __launch_bounds__(256) void cvt_bf16_kernel(const void* __restrict__ src,
                                                       bf16* __restrict__ dst, int n,
                                                       const int* __restrict__ flag) {
    int i = blockIdx.x * 256 + threadIdx.x;
    if (i < n) {
        if (*flag)
            dst[i] = (bf16)((const float*)src)[i];
        else
            dst[i] = ((const bf16*)src)[i];
    }
}

__global__ __launch_bounds__(256) void cvt_f32_kernel(const void* __restrict__ src,
                                                      float* __restrict__ dst, int n,
                                                      const int* __restrict__ flag) {
    int i = blockIdx.x * 256 + threadIdx.x;
    if (i < n) {
        if (*flag)
            dst[i] = ((const float*)src)[i];
        else
            dst[i] = (float)((const bf16*)src)[i];
    }
}

// ---------------------------------------------------------------------------
// Zero the S-padding rows of q/k and padding cols of v^T.
// ---------------------------------------------------------------------------
__global__ __launch_bounds__(256) void zeropad_kernel(bf16* __restrict__ q_ws,
                                                      bf16* __restrict__ k_ws,
                                                      bf16* __restrict__ vt_ws) {
    int t = blockIdx.x * 256 + threadIdx.x;          // 96 bh * 4 s * 64 dh = 24576
    if (t < kB * kH * (kSP - kS) * kDH) {
        int bh  = t >> 8;
        int rem = t & 255;
        int s   = kS + (rem >> 6);
        int dh  = rem & 63;
        size_t qi = ((size_t)bh * kSP + s) * kDH + dh;
        q_ws[qi] = (bf16)0.f;
        k_ws[qi] = (bf16)0.f;
        size_t vi = ((size_t)bh * kDH + dh) * kSP + s;
        vt_ws[vi] = (bf16)0.f;
    }
}

// ---------------------------------------------------------------------------
// m97-structure GEMM core (UNCHANGED): 128x128 tile, BK=32, 4 waves,
// 4x4 acc per wave, global_load_lds width-16 staging.
// ---------------------------------------------------------------------------
__device__ __forceinline__ void async_copy16(const bf16* g, bf16* l) {
    __builtin_amdgcn_global_load_lds(
        (const __attribute__((address_space(1))) void*)g,
        (__attribute__((address_space(3))) void*)l,
        16, 0, 0);
}

__device__ __forceinline__ void gemm128_core(const bf16* __restrict__ X,
                                             const bf16* __restrict__ W,
                                             int m0, int n0,
                                             bf16* Asm, bf16* Bsm,
                                             floatx4 acc[4][4]) {
    const int tid  = threadIdx.x;
    const int lane = tid & 63;
    const int w    = tid >> 6;
    const int srow = (w << 4) + (lane >> 2);
    const int scol = (lane & 3) << 3;
    const int lrow = lane & 15;
    const int lq   = lane >> 4;
    const int wm   = (w >> 1) << 6;
    const int wn   = (w & 1) << 6;

    const bf16* gA = X + (size_t)(m0 + srow) * kD + scol;
    const bf16* gB = W + (size_t)(n0 + srow) * kD + scol;
    bf16* lA = Asm + (w << 9);     // wave-uniform base; HW adds lane*16B
    bf16* lB = Bsm + (w << 9);

    for (int k0 = 0; k0 < kD; k0 += 32) {
        async_copy16(gA + k0, lA);
        async_copy16(gA + (size_t)64 * kD + k0, lA + 2048);
        async_copy16(gB + k0, lB);
        async_copy16(gB + (size_t)64 * kD + k0, lB + 2048);
        __syncthreads();

        bf16x8 af[4], bfr[4];
#pragma unroll
        for (int i = 0; i < 4; i++)
            af[i] = *(const bf16x8*)(Asm + ((wm + i * 16 + lrow) << 5) + (lq << 3));
#pragma unroll
        for (int j = 0; j < 4; j++)
            bfr[j] = *(const bf16x8*)(Bsm + ((wn + j * 16 + lrow) << 5) + (lq << 3));
#pragma unroll
        for (int i = 0; i < 4; i++)
#pragma unroll
            for (int j = 0; j < 4; j++)
                acc[i][j] = __builtin_amdgcn_mfma_f32_16x16x32_bf16(
                    af[i], bfr[j], acc[i][j], 0, 0, 0);
        __syncthreads();
    }
}

__global__ __launch_bounds__(256) void qkv_kernel(const bf16* __restrict__ X,
                                                  const bf16* __restrict__ Wq,
                                                  const bf16* __restrict__ Wk,
                                                  const bf16* __restrict__ Wv,
                                                  const float* __restrict__ bq,
                                                  const float* __restrict__ bv,
                                                  bf16* __restrict__ q_ws,
                                                  bf16* __restrict__ k_ws,
                                                  bf16* __restrict__ vt_ws) {
    __shared__ bf16 Asm[128 * 32];
    __shared__ bf16 Bsm[128 * 32];

    const int m0  = blockIdx.x << 7;
    const int mat = blockIdx.y / 6;
    const int n0  = (blockIdx.y % 6) << 7;
    const bf16* W = (mat == 0) ? Wq : (mat == 1) ? Wk : Wv;

    floatx4 acc[4][4] = {};
    gemm128_core(X, W, m0, n0, Asm, Bsm, acc);

    const int tid  = threadIdx.x;
    const int lane = tid & 63;
    const int w    = tid >> 6;
    const int lrow = lane & 15;
    const int lq   = lane >> 4;
    const int wm   = (w >> 1) << 6;
    const int wn   = (w & 1) << 6;

#pragma unroll
    for (int i = 0; i < 4; i++) {
#pragma unroll
        for (int j = 0; j < 4; j++) {
            const int n  = n0 + wn + j * 16 + lrow;
            const int hh = n >> 6, dh = n & 63;
            const float bval = (mat == 0) ? bq[n] : (mat == 2) ? bv[n] : 0.f;
#pragma unroll
            for (int r = 0; r < 4; r++) {
                const int m = m0 + wm + i * 16 + lq * 4 + r;
                if (m >= kM) continue;
                float v = acc[i][j][r];
                if (mat == 0)      v = (v + bval) * kScale;
                else if (mat == 2) v = v + bval;
                const int bb = m / kS, s = m - bb * kS;
                if (mat == 2)
                    vt_ws[(((size_t)(bb * kH + hh)) * kDH + dh) * kSP + s] = (bf16)v;
                else if (mat == 1)
                    k_ws[(((size_t)(bb * kH + hh)) * kSP + s) * kDH + dh] = (bf16)v;
                else
                    q_ws[(((size_t)(bb * kH + hh)) * kSP + s) * kDH + dh] = (bf16)v;
            }
        }
    }
}

__global__ __launch_bounds__(256) void out_kernel(const bf16* __restrict__ X,
                                                  const bf16* __restrict__ Wo,
                                                  const float* __restrict__ bo,
                                                  float* __restrict__ outf) {
    __shared__ bf16 Asm[128 * 32];
    __shared__ bf16 Bsm[128 * 32];

    const int m0 = blockIdx.x << 7;
    const int n0 = blockIdx.y << 7;

    floatx4 acc[4][4] = {};
    gemm128_core(X, Wo, m0, n0, Asm, Bsm, acc);

    const int tid  = threadIdx.x;
    const int lane = tid & 63;
    const int w    = tid >> 6;
    const int lrow = lane & 15;
    const int lq   = lane >> 4;
    const int wm   = (w >> 1) << 6;
    const int wn   = (w & 1) << 6;

#pragma unroll
    for (int i = 0; i < 4; i++) {
#pragma unroll
        for (int j = 0; j < 4; j++) {
            const int n = n0 + wn + j * 16 + lrow;
            const float bval = bo[n];
#pragma unroll
            for (int r = 0; r < 4; r++) {
                const int m = m0 + wm + i * 16 + lq * 4 + r;
                if (m >= kM) continue;
                outf[(size_t)m * kD + n] = acc[i][j][r] + bval;
            }
        }
    }
}

// ---------------------------------------------------------------------------
// Flash attention v7: K/V staged in LDS via global_load_lds, double-buffered,
// shared by all 4 waves (4x fewer global loads; prefetch lives in the DMA
// queue which the compiler cannot sink — drained once per chunk at the
// barrier, after a full chunk of compute has covered the L2/L3 latency).
//
// Tiles are [64 rows][64 bf16 = 128 B] -> naive ds_read_b128 at column
// slices is a 16-way bank conflict; fixed with the m214 XOR swizzle
// (cb ^= (row&7)<<4), applied as: LINEAR LDS dest (required by
// global_load_lds) + inverse-swizzled GLOBAL source + swizzled read.
// Tail (chunk 23): out-of-range source rows clamped to valid data (finite),
// masked exp gives exact-zero P columns, so full-width PV stays correct.
// All waves (incl. q-range-exhausted ones) participate in staging+barriers.
// ---------------------------------------------------------------------------
__device__ __forceinline__ const bf16* lds_at(const bf16* sm, int row, int cb) {
    // row-major [64][128B] tile with XOR bank swizzle on the byte column
    return sm + row * 64 + ((cb ^ ((row & 7) << 4)) >> 1);
}

// Stage one 64x64 bf16 tile (8 KB = 8 stripes of 1 KB; stripe = wave-issue).
// LDS dest linear: stripe sidx covers rows sidx*8 .. sidx*8+7.
// Lane l -> LDS row = sidx*8 + l/8, byte col cb = (l%8)*16; global source
// fetches the inverse-swizzled column so that swizzled reads see K[row][cb].
__device__ __forceinline__ void stage_k(const bf16* __restrict__ kbase, int s0,
                                        bf16* ksm, int w, int lane) {
#pragma unroll
    for (int i = 0; i < 2; i++) {
        const int sidx = i * 4 + w;
        const int row  = sidx * 8 + (lane >> 3);
        const int cb   = (lane & 7) << 4;
        const int scb  = cb ^ ((row & 7) << 4);
        int gr = s0 + row;
        if (gr >= kSP) gr = 1472;                    // tail clamp (finite data)
        async_copy16(kbase + (size_t)gr * kDH + (scb >> 1), ksm + sidx * 512);
    }
}

__device__ __forceinline__ void stage_v(const bf16* __restrict__ vbase, int s0,
                                        bf16* vsm, int w, int lane) {
#pragma unroll
    for (int i = 0; i < 2; i++) {
        const int sidx = i * 4 + w;
        const int row  = sidx * 8 + (lane >> 3);     // dh
        const int cb   = (lane & 7) << 4;
        const int scb  = cb ^ ((row & 7) << 4);
        int key = s0 + (scb >> 1);
        if (key >= kSP) key = 1472;                  // tail clamp (finite data)
        async_copy16(vbase + (size_t)row * kSP + key, vsm + sidx * 512);
    }
}

__device__ __forceinline__ void qk_mfma_lds(const bf16* ksm,
                                            const bf16x8 qf[2][2],
                                            floatx4 sc[2][4],
                                            int col, int quad) {
#pragma unroll
    for (int t = 0; t < 4; t++) {
        const int r = 16 * t + col;
        const bf16x8 kf0 = *(const bf16x8*)lds_at(ksm, r, quad * 16);
        const bf16x8 kf1 = *(const bf16x8*)lds_at(ksm, r, 64 + quad * 16);
        __builtin_amdgcn_s_setprio(1);
#pragma unroll
        for (int qt = 0; qt < 2; qt++) {
            floatx4 a = {0.f, 0.f, 0.f, 0.f};
            a = __builtin_amdgcn_mfma_f32_16x16x32_bf16(kf0, qf[qt][0], a, 0, 0, 0);
            a = __builtin_amdgcn_mfma_f32_16x16x32_bf16(kf1, qf[qt][1], a, 0, 0, 0);
            sc[qt][t] = a;
        }
        __builtin_amdgcn_s_setprio(0);
    }
}

template <bool MASK>
__device__ __forceinline__ void exp_store(const floatx4 sc[2][4],
                                          bf16* __restrict__ Pw,
                                          float lsum[2],
                                          int s0, int col, int quad) {
#pragma unroll
    for (int qt = 0; qt < 2; qt++)
#pragma unroll
        for (int t = 0; t < 4; t++) {
            bf16x4 pv;
#pragma unroll
            for (int r = 0; r < 4; r++) {
                float p;
                if (MASK && (s0 + 16 * t + quad * 4 + r >= kS))
                    p = 0.f;
                else
                    p = __expf(sc[qt][t][r]);
                lsum[qt] += p;
                pv[r] = (bf16)p;
            }
            *(bf16x4*)(Pw + (qt * 16 + col) * kPSTR + 16 * t + quad * 4) = pv;
        }
}

__device__ __forceinline__ void pv_lds(const bf16* vsm,
                                       const bf16* __restrict__ Pr,
                                       floatx4 Oacc[2][4],
                                       int col, int quad) {
    bf16x8 pa[2][2];
#pragma unroll
    for (int qt = 0; qt < 2; qt++)
#pragma unroll
        for (int kc = 0; kc < 2; kc++)
            pa[qt][kc] = *(const bf16x8*)(Pr + (qt * 16 + col) * kPSTR + kc * 32 + quad * 8);
#pragma unroll
    for (int n = 0; n < 4; n++) {
        const int row = n * 16 + col;                // dh row of V^T tile
#pragma unroll
        for (int kc = 0; kc < 2; kc++) {
            const bf16x8 vf = *(const bf16x8*)lds_at(vsm, row, kc * 64 + quad * 16);
            __builtin_amdgcn_s_setprio(1);
#pragma unroll
            for (int qt = 0; qt < 2; qt++)
                Oacc[qt][n] = __builtin_amdgcn_mfma_f32_16x16x32_bf16(
                    pa[qt][kc], vf, Oacc[qt][n], 0, 0, 0);
            __builtin_amdgcn_s_setprio(0);
        }
    }
}

__global__ __launch_bounds__(256, 2) void fattn_kernel(const bf16* __restrict__ q_ws,
                                                       const bf16* __restrict__ k_ws,
                                                       const bf16* __restrict__ vt_ws,
                                                       bf16* __restrict__ ctx) {
    __shared__ bf16 Ksm[2][64 * 64];       // 16 KB double-buffered K tile
    __shared__ bf16 Vsm[2][64 * 64];       // 16 KB double-buffered V^T tile
    __shared__ bf16 Pbuf[4][32 * kPSTR];   // 18 KB per-wave P slices -> 50 KB total

    const int idx = blockIdx.x;         // 0..1151; bh fastest -> idx%8 = bh%8 (XCD)
    const int bh  = idx % 96;
    const int qb  = idx / 96;           // 0..11, 128 Q rows per block
    const int b   = bh / kH;
    const int h   = bh - b * kH;
    const int tid  = threadIdx.x;
    const int w    = tid >> 6;
    const int lane = tid & 63;
    const int col  = lane & 15;         // q index within a 16-row tile
    const int quad = lane >> 4;
    const int q0   = qb * 128 + w * 32; // this wave's 32 Q rows (2 tiles)
    const bool active = (q0 < kS);      // wave-uniform; inactive waves still
                                        // stage + hit every barrier

    const bf16* qbase = q_ws  + (size_t)bh * kSP * kDH;
    const bf16* kbase = k_ws  + (size_t)bh * kSP * kDH;
    const bf16* vbase = vt_ws + (size_t)bh * kDH * kSP;

    bf16x8 qf[2][2] = {};
    if (active) {
#pragma unroll
        for (int qt = 0; qt < 2; qt++) {
            const bf16* qr = qbase + (size_t)(q0 + qt * 16 + col) * kDH + quad * 8;
            qf[qt][0] = *(const bf16x8*)(qr);
            qf[qt][1] = *(const bf16x8*)(qr + 32);
        }
    }

    float lsum[2] = {0.f, 0.f};
    floatx4 Oacc[2][4];
#pragma unroll
    for (int qt = 0; qt < 2; qt++)
#pragma unroll
        for (int n = 0; n < 4; n++) Oacc[qt][n] = (floatx4){0.f, 0.f, 0.f, 0.f};

    bf16* const P = &Pbuf[w][0];
    floatx4 sc[2][4];

    // prologue: stage chunk 0
    stage_k(kbase, 0, &Ksm[0][0], w, lane);
    stage_v(vbase, 0, &Vsm[0][0], w, lane);
    __syncthreads();

    int buf = 0;
    // chunks 0..22: stage next, compute current, one barrier per chunk
    for (int c = 0; c < 23; ++c) {
        stage_k(kbase, (c + 1) * 64, &Ksm[buf ^ 1][0], w, lane);
        stage_v(vbase, (c + 1) * 64, &Vsm[buf ^ 1][0], w, lane);
        if (active) {
            qk_mfma_lds(&Ksm[buf][0], qf, sc, col, quad);
            exp_store<false>(sc, P, lsum, c * 64, col, quad);
            pv_lds(&Vsm[buf][0], P, Oacc, col, quad);
        }
        __syncthreads();
        buf ^= 1;
    }
    // chunk 23 (keys 1472..1535; >=1500 masked to exact-zero P)
    if (active) {
        qk_mfma_lds(&Ksm[buf][0], qf, sc, col, quad);
        exp_store<true>(sc, P, lsum, 1472, col, quad);
        pv_lds(&Vsm[buf][0], P, Oacc, col, quad);

#pragma unroll
        for (int qt = 0; qt < 2; qt++) {
            float l = lsum[qt];
            l += __shfl_xor(l, 16);
            l += __shfl_xor(l, 32);
            const float rinv_col = 1.0f / l;         // for q = col of this tile
            float ri[4];
#pragma unroll
            for (int r = 0; r < 4; r++)
                ri[r] = __shfl(rinv_col, quad * 4 + r, 16);
#pragma unroll
            for (int n = 0; n < 4; n++)
#pragma unroll
                for (int r = 0; r < 4; r++) {
                    const int q = q0 + qt * 16 + quad * 4 + r;
                    if (q < kS)
                        ctx[((size_t)(b * kS + q)) * kD + h * kDH + n * 16 + col] =
                            (bf16)(Oacc[qt][n][r] * ri[r]);
                }
        }
    }
}

// ---------------------------------------------------------------------------
extern "C" void kernel_launch(void* const* d_in, const int* in_sizes, int n_in,
                              void* d_out, int out_size, void* d_ws, size_t ws_size,
                              hipStream_t stream) {
    float* out_f = (float*)d_out;   // reference output dtype is float32

    constexpr size_t nX = (size_t)kM * kD;
    constexpr size_t nW = (size_t)kD * kD;
    constexpr size_t per_qkv = (size_t)kB * kH * kSP * kDH;

    bf16* xb    = (bf16*)d_ws;
    bf16* Wqb   = xb + nX;
    bf16* Wkb   = Wqb + nW;
    bf16* Wvb   = Wkb + nW;
    bf16* Wob   = Wvb + nW;
    bf16* q_ws  = Wob + nW;
    bf16* k_ws  = q_ws + per_qkv;
    bf16* vt_ws = k_ws + per_qkv;
    float* bqf  = (float*)(vt_ws + per_qkv);
    float* bvf  = bqf + kD;
    float* bof  = bvf + kD;
    int*  flag  = (int*)(bof + kD);
    bf16* ctx   = xb;   // alias: xb last read by qkv_kernel, ctx written after

    // 1) dtype probe + input normalization to bf16 (biases to f32)
    detect_kernel<<<1, 256, 0, stream>>>(d_in[0], flag);
    cvt_bf16_kernel<<<(int)((nX + 255) / 256), 256, 0, stream>>>(d_in[0], xb,  (int)nX, flag);
    cvt_bf16_kernel<<<(int)((nW + 255) / 256), 256, 0, stream>>>(d_in[1], Wqb, (int)nW, flag);
    cvt_bf16_kernel<<<(int)((nW + 255) / 256), 256, 0, stream>>>(d_in[3], Wkb, (int)nW, flag);
    cvt_bf16_kernel<<<(int)((nW + 255) / 256), 256, 0, stream>>>(d_in[4], Wvb, (int)nW, flag);
    cvt_bf16_kernel<<<(int)((nW + 255) / 256), 256, 0, stream>>>(d_in[6], Wob, (int)nW, flag);
    cvt_f32_kernel<<<3, 256, 0, stream>>>(d_in[2], bqf, kD, flag);
    cvt_f32_kernel<<<3, 256, 0, stream>>>(d_in[5], bvf, kD, flag);
    cvt_f32_kernel<<<3, 256, 0, stream>>>(d_in[7], bof, kD, flag);

    // 2) fused QKV projection (+ padding): grid 94 x (3 mats * 6 n-blocks)
    zeropad_kernel<<<96, 256, 0, stream>>>(q_ws, k_ws, vt_ws);
    dim3 qkvgrid((kM + 127) / 128, 18);   // 94 x 18 = 1692 blocks
    qkv_kernel<<<qkvgrid, 256, 0, stream>>>(xb, Wqb, Wkb, Wvb, bqf, bvf,
                                            q_ws, k_ws, vt_ws);

    // 3) flash attention (1D grid: 12 q-blocks x 96 bh, bh fastest for XCD pin)
    fattn_kernel<<<dim3(12 * 96), 256, 0, stream>>>(q_ws, k_ws, vt_ws, ctx);

    // 4) output projection -> float32 d_out
    dim3 ogrid((kM + 127) / 128, kD / 128);   // 94 x 6
    out_kernel<<<ogrid, 256, 0, stream>>>(ctx, Wob, bof, out_f);
}